// Round 7
// baseline (305.145 us; speedup 1.0000x reference)
//
#include <hip/hip_runtime.h>
#include <hip/hip_bf16.h>
#include <math.h>

typedef __bf16 bhalf8 __attribute__((ext_vector_type(8)));
typedef __bf16 bhalf4 __attribute__((ext_vector_type(4)));
typedef float  f32x4  __attribute__((ext_vector_type(4)));

#define MFMA16(a, b, c) __builtin_amdgcn_mfma_f32_16x16x32_bf16(a, b, c, 0, 0, 0)

// ---------------------------------------------------------------------------
// Batched weight transpose+cast: all four weights into one contiguous
// Wt[2560][512] (wqt | wkvt | wrelt | wot). grid (8, 640), 256 thr.
// ---------------------------------------------------------------------------
__global__ __launch_bounds__(256) void transcast_all(
    const float* __restrict__ Wq, const float* __restrict__ Wkv,
    const float* __restrict__ Wrel, const float* __restrict__ Wo,
    __bf16* __restrict__ Wt)
{
  const int k  = blockIdx.x * 64 + (threadIdx.x & 63);
  const int ng = blockIdx.y * 4 + (threadIdx.x >> 6);
  const float* src; int nn, Ns;
  if (ng < 512)       { src = Wq;   nn = ng;        Ns = 512; }
  else if (ng < 1536) { src = Wkv;  nn = ng - 512;  Ns = 1024; }
  else if (ng < 2048) { src = Wrel; nn = ng - 1536; Ns = 512; }
  else                { src = Wo;   nn = ng - 2048; Ns = 512; }
  Wt[(size_t)ng * 512 + k] = (__bf16)src[(size_t)k * Ns + nn];
}

// ---------------------------------------------------------------------------
// bf16 MFMA GEMM: C[M][N] = A[M][K] @ Bt[N][K]^T
// A_F32: A rows are f32, converted during staging; split handles concat(A0,A1).
// OUT_MODE 0: bf16 C; 1: f32 C; 2: attention-Q epilogue -> qup/qvp
// ---------------------------------------------------------------------------
template <int OUT_MODE, int A_F32>
__global__ __launch_bounds__(256) void gemm_bf16(
    const void* __restrict__ A0v, const void* __restrict__ A1v, int split,
    const __bf16* __restrict__ Bt, void* __restrict__ C, int M, int N, int K,
    const float* __restrict__ pbu, const float* __restrict__ pbv,
    __bf16* __restrict__ qup, __bf16* __restrict__ qvp)
{
  __shared__ __bf16 a_lds[128][40];
  __shared__ __bf16 b_lds[128][40];
  const int m0 = blockIdx.x * 128;
  const int n0 = blockIdx.y * 128;
  const int tid = threadIdx.x;
  const int w = tid >> 6, l = tid & 63;
  const int wn = (w >> 1) * 64, wm = (w & 1) * 64;
  const int li = l & 15, lq = l >> 4;
  const int lk = lq << 3;

  // staging rows for the two 256-thread chunks
  const int srow0 = tid >> 2, srow1 = (tid >> 2) + 64;
  const int skc = (tid & 3) << 3;
  const float* arowf[2];
  const __bf16* arowh[2];
  if (A_F32) {
    const float* A0 = (const float*)A0v;
    const float* A1 = (const float*)A1v;
    const int r0 = m0 + srow0, r1 = m0 + srow1;
    arowf[0] = r0 < split ? A0 + (size_t)r0 * K : A1 + (size_t)(r0 - split) * K;
    arowf[1] = r1 < split ? A0 + (size_t)r1 * K : A1 + (size_t)(r1 - split) * K;
  } else {
    arowh[0] = (const __bf16*)A0v + (size_t)(m0 + srow0) * K;
    arowh[1] = (const __bf16*)A0v + (size_t)(m0 + srow1) * K;
  }

  f32x4 acc[4][4] = {};

  for (int k0 = 0; k0 < K; k0 += 32) {
    __syncthreads();
#pragma unroll
    for (int c = 0; c < 2; ++c) {
      const int row = c ? srow1 : srow0;
      if (A_F32) {
        float4 f0 = *(const float4*)(arowf[c] + k0 + skc);
        float4 f1 = *(const float4*)(arowf[c] + k0 + skc + 4);
        bhalf8 h;
        h[0] = (__bf16)f0.x; h[1] = (__bf16)f0.y; h[2] = (__bf16)f0.z; h[3] = (__bf16)f0.w;
        h[4] = (__bf16)f1.x; h[5] = (__bf16)f1.y; h[6] = (__bf16)f1.z; h[7] = (__bf16)f1.w;
        *(bhalf8*)&a_lds[row][skc] = h;
      } else {
        *(bhalf8*)&a_lds[row][skc] = *(const bhalf8*)(arowh[c] + k0 + skc);
      }
      *(bhalf8*)&b_lds[row][skc] = *(const bhalf8*)(Bt + (size_t)(n0 + row) * K + k0 + skc);
    }
    __syncthreads();
    bhalf8 af[4], bf_[4];
#pragma unroll
    for (int s = 0; s < 4; ++s) {
      af[s]  = *(const bhalf8*)&b_lds[wn + s * 16 + li][lk];
      bf_[s] = *(const bhalf8*)&a_lds[wm + s * 16 + li][lk];
    }
#pragma unroll
    for (int ns = 0; ns < 4; ++ns)
#pragma unroll
      for (int ms = 0; ms < 4; ++ms)
        acc[ns][ms] = MFMA16(af[ns], bf_[ms], acc[ns][ms]);
  }

  const int lr = lq << 2;
#pragma unroll
  for (int ms = 0; ms < 4; ++ms) {
    const int m = m0 + wm + ms * 16 + li;
#pragma unroll
    for (int ns = 0; ns < 4; ++ns) {
      const int n = n0 + wn + ns * 16 + lr;
      if (OUT_MODE == 1) {
        *(f32x4*)((float*)C + (size_t)m * N + n) = acc[ns][ms];
      } else if (OUT_MODE == 0) {
        bhalf4 pk;
#pragma unroll
        for (int r = 0; r < 4; ++r) pk[r] = (__bf16)acc[ns][ms][r];
        *(bhalf4*)((__bf16*)C + (size_t)m * N + n) = pk;
      } else {
        const int i = m >> 2, bb = m & 3, hd = n >> 6;
        float4 u4 = *(const float4*)(pbu + n);
        float4 v4 = *(const float4*)(pbv + n);
        const size_t off = (((size_t)bb * 8 + hd) * 512 + i) * 64 + (n & 63);
        bhalf4 pu, pv;
        pu[0] = (__bf16)((acc[ns][ms][0] + u4.x) * 0.125f);
        pu[1] = (__bf16)((acc[ns][ms][1] + u4.y) * 0.125f);
        pu[2] = (__bf16)((acc[ns][ms][2] + u4.z) * 0.125f);
        pu[3] = (__bf16)((acc[ns][ms][3] + u4.w) * 0.125f);
        pv[0] = (__bf16)((acc[ns][ms][0] + v4.x) * 0.125f);
        pv[1] = (__bf16)((acc[ns][ms][1] + v4.y) * 0.125f);
        pv[2] = (__bf16)((acc[ns][ms][2] + v4.z) * 0.125f);
        pv[3] = (__bf16)((acc[ns][ms][3] + v4.w) * 0.125f);
        *(bhalf4*)(qup + off) = pu;
        *(bhalf4*)(qvp + off) = pv;
      }
    }
  }
}

// ---------------------------------------------------------------------------
// V transpose: vtb[plane][d][t]
// ---------------------------------------------------------------------------
__global__ __launch_bounds__(256) void vtrans(const __bf16* __restrict__ kvb,
                                              __bf16* __restrict__ vtb)
{
  __shared__ __bf16 T2[64][72];
  const int t0 = blockIdx.x * 64;
  const int p = blockIdx.y;
  const int b = p >> 3, n = p & 7;
  const int tid = threadIdx.x;
#pragma unroll
  for (int c = 0; c < 2; ++c) {
    const int e = c * 256 + tid;
    const int tl = e >> 3, d8 = (e & 7) << 3;
    bhalf8 v8 = *(const bhalf8*)(kvb + ((size_t)(t0 + tl) * 4 + b) * 1024 + 512 + n * 64 + d8);
#pragma unroll
    for (int j = 0; j < 8; ++j) T2[d8 + j][tl] = v8[j];
  }
  __syncthreads();
#pragma unroll
  for (int c = 0; c < 2; ++c) {
    const int e = c * 256 + tid;
    const int d = e >> 3, t8 = (e & 7) << 3;
    bhalf8 v = *(const bhalf8*)&T2[d][t8];
    *(bhalf8*)(vtb + ((size_t)p * 64 + d) * 2048 + t0 + t8) = v;
  }
}

// ---------------------------------------------------------------------------
// Fused flash attention, split-K: grid 1024 = (plane, i0-block, half).
// half 0: tiles [0,8); half 1: tiles [8,nt). Inner loop identical to r6.
// Emits per-half unnormalized O (po, f32) and (m,l) (mlh); streams P (pb)
// and tile maxes (ms) as before.
// ---------------------------------------------------------------------------
__global__ __launch_bounds__(512, 4) void attn_v4(
    const __bf16* __restrict__ qup, const __bf16* __restrict__ qvp,
    const __bf16* __restrict__ kvb, const __bf16* __restrict__ relb,
    const __bf16* __restrict__ vtb, const float* __restrict__ indice,
    float* __restrict__ po, float* __restrict__ mlh,
    __bf16* __restrict__ pb, float* __restrict__ ms)
{
  __shared__ __align__(16) __bf16 P_l[32][136];
  __shared__ __align__(16) __bf16 bdl[160][34];
  __shared__ float red0[8][33];
  __shared__ float red1[8][33];

  const int bid = blockIdx.x;
  const int wrk = ((bid & 7) << 7) | (bid >> 3);   // 1024 % 8 == 0, bijective
  const int plane = wrk >> 5;
  const int i0 = ((wrk >> 1) & 15) << 5;
  const int half = wrk & 1;
  const int b = plane >> 3, n = plane & 7;
  const int tid = threadIdx.x;
  const int w = tid >> 6;
  const int l = tid & 63;
  const int li = l & 15;
  const int lq = l >> 4;

  const __bf16* kbase = kvb + (size_t)b * 1024 + n * 64;
  const __bf16* rbase = relb + (size_t)b * 512 + n * 64;
  const __bf16* vbase = vtb + (size_t)plane * 131072;

  bhalf8 qu[2][2], qv[2][2];
  float g[2][4];
#pragma unroll
  for (int it = 0; it < 2; ++it) {
    const int i = i0 + it * 16 + li;
    const float* gp = indice + ((size_t)i * 4 + b) * 4;
    g[it][0] = gp[0]; g[it][1] = gp[1]; g[it][2] = gp[2]; g[it][3] = gp[3];
    const __bf16* qp = qup + ((size_t)plane * 512 + i) * 64;
    const __bf16* qq = qvp + ((size_t)plane * 512 + i) * 64;
    qu[it][0] = *(const bhalf8*)(qp + lq * 8);
    qu[it][1] = *(const bhalf8*)(qp + 32 + lq * 8);
    qv[it][0] = *(const bhalf8*)(qq + lq * 8);
    qv[it][1] = *(const bhalf8*)(qq + 32 + lq * 8);
  }

  float m0 = -1e30f, m1 = -1e30f, l0 = 0.f, l1 = 0.f;
  f32x4 oacc = {0.f, 0.f, 0.f, 0.f};
  const int dgw = w >> 1, itw = w & 1;
  const int nt = ((1536 + i0 + 31) >> 7) + 1;
  const int t_start = half ? 8 : 0;
  const int t_end   = half ? nt : 8;

  for (int tile = t_start; tile < t_end; ++tile) {
    const int tb = tile << 7;
    const int rb = tb + 480 - i0;

    // ---- BD ----
#pragma unroll
    for (int ri = 0; ri < 2; ++ri) {
      const int rs = w + ri * 8;
      if (ri == 0 || rs < 10) {
        int row = rb + rs * 16 + li;
        row = row > 2047 ? 2047 : row;
        const __bf16* rp = rbase + (size_t)row * 2048;
        bhalf8 a0 = *(const bhalf8*)(rp + lq * 8);
        bhalf8 a1 = *(const bhalf8*)(rp + 32 + lq * 8);
#pragma unroll
        for (int it = 0; it < 2; ++it) {
          f32x4 c = {0.f, 0.f, 0.f, 0.f};
          c = MFMA16(a0, qv[it][0], c);
          c = MFMA16(a1, qv[it][1], c);
#pragma unroll
          for (int r = 0; r < 4; ++r) {
            const int rowl = rs * 16 + lq * 4 + r;
            int rk = (rb + rowl) >> 9; rk = rk > 3 ? 3 : rk;
            bdl[rowl][it * 16 + li] = (__bf16)(c[r] * g[it][rk]);
          }
        }
      }
    }
    // ---- AC ----
    f32x4 s[2];
    {
      const __bf16* kp = kbase + (size_t)(tb + w * 16 + li) * 4096;
      bhalf8 a0 = *(const bhalf8*)(kp + lq * 8);
      bhalf8 a1 = *(const bhalf8*)(kp + 32 + lq * 8);
#pragma unroll
      for (int it = 0; it < 2; ++it) {
        f32x4 c = {0.f, 0.f, 0.f, 0.f};
        c = MFMA16(a0, qu[it][0], c);
        c = MFMA16(a1, qu[it][1], c);
        s[it] = c;
      }
    }
    __syncthreads();   // bd visible

    float sv[2][4];
    float tmax[2] = {-1e30f, -1e30f};
#pragma unroll
    for (int it = 0; it < 2; ++it) {
      const int i = i0 + it * 16 + li;
#pragma unroll
      for (int r = 0; r < 4; ++r) {
        const int tl = w * 16 + lq * 4 + r;
        const int t = tb + tl;
        float sc = -1e30f;
        if (t <= 1536 + i) {
          const float bdv = (float)bdl[tl + 31 - it * 16 - li][it * 16 + li];
          sc = s[it][r] * g[it][t >> 9] + bdv;
        }
        sv[it][r] = sc;
        tmax[it] = fmaxf(tmax[it], sc);
      }
    }
    tmax[0] = fmaxf(tmax[0], __shfl_xor(tmax[0], 16));
    tmax[0] = fmaxf(tmax[0], __shfl_xor(tmax[0], 32));
    tmax[1] = fmaxf(tmax[1], __shfl_xor(tmax[1], 16));
    tmax[1] = fmaxf(tmax[1], __shfl_xor(tmax[1], 32));
    if (l < 16) { red0[w][li] = tmax[0]; red0[w][16 + li] = tmax[1]; }
    __syncthreads();

    float mn[2], scl[2];
#pragma unroll
    for (int it = 0; it < 2; ++it) {
      const int ic = it * 16 + li;
      float mt = red0[0][ic];
#pragma unroll
      for (int ww = 1; ww < 8; ++ww) mt = fmaxf(mt, red0[ww][ic]);
      const float mo = it ? m1 : m0;
      mn[it] = fmaxf(mo, mt);
      scl[it] = __expf(mo - mn[it]);
    }
    // record this tile's reference max for am_final
    if (w == 0 && l < 16) {
      float* msp = ms + ((size_t)plane * 16 + tile) * 512 + i0;
      msp[li] = mn[0];
      msp[16 + li] = mn[1];
    }
    float ps[2] = {0.f, 0.f};
#pragma unroll
    for (int it = 0; it < 2; ++it) {
      bhalf4 pk;
#pragma unroll
      for (int r = 0; r < 4; ++r) {
        const float p = __expf(sv[it][r] - mn[it]);
        ps[it] += p;
        pk[r] = (__bf16)p;
      }
      *(bhalf4*)&P_l[it * 16 + li][w * 16 + lq * 4] = pk;
    }
    ps[0] += __shfl_xor(ps[0], 16); ps[0] += __shfl_xor(ps[0], 32);
    ps[1] += __shfl_xor(ps[1], 16); ps[1] += __shfl_xor(ps[1], 32);
    if (l < 16) { red1[w][li] = ps[0]; red1[w][16 + li] = ps[1]; }
    __syncthreads();   // red1 + P_l visible

    // stream P tile to global
    {
      const int iloc = tid >> 4, tq = tid & 15;
      bhalf8 pv8 = *(const bhalf8*)&P_l[iloc][tq * 8];
      *(bhalf8*)(pb + ((size_t)plane * 512 + i0 + iloc) * 2048 + tb + tq * 8) = pv8;
    }

    {
      float ls0 = 0.f, ls1 = 0.f;
#pragma unroll
      for (int ww = 0; ww < 8; ++ww) { ls0 += red1[ww][li]; ls1 += red1[ww][16 + li]; }
      l0 = l0 * scl[0] + ls0; m0 = mn[0];
      l1 = l1 * scl[1] + ls1; m1 = mn[1];
    }
    // ---- PV ----
    oacc *= scl[itw];
    {
      const __bf16* vp = vbase + (size_t)(dgw * 16 + li) * 2048 + tb;
#pragma unroll
      for (int kt = 0; kt < 4; ++kt) {
        bhalf8 af = *(const bhalf8*)(vp + kt * 32 + lq * 8);
        bhalf8 bf_ = *(const bhalf8*)&P_l[itw * 16 + li][kt * 32 + lq * 8];
        oacc = MFMA16(af, bf_, oacc);
      }
    }
  }

  // ---- epilogue: per-half unnormalized O + (m,l) ----
  __syncthreads();
  float* obuf = (float*)&P_l[0][0];   // 32x68 f32
  if (w == 0 && l < 16) {
    float* mp0 = mlh + ((size_t)half * 16384 + plane * 512 + i0 + li) * 2;
    mp0[0] = m0; mp0[1] = l0;
    float* mp1 = mlh + ((size_t)half * 16384 + plane * 512 + i0 + 16 + li) * 2;
    mp1[0] = m1; mp1[1] = l1;
  }
#pragma unroll
  for (int r = 0; r < 4; ++r)
    obuf[(itw * 16 + li) * 68 + dgw * 16 + lq * 4 + r] = oacc[r];
  __syncthreads();
  {
    const int iloc = tid >> 4, dq = tid & 15;
    f32x4 o = *(f32x4*)&obuf[iloc * 68 + dq * 4];
    *(f32x4*)(po + ((size_t)half * 16384 + plane * 512 + i0 + iloc) * 64 + dq * 4) = o;
  }
}

// ---------------------------------------------------------------------------
// Merge the two key-halves: vec = (o_a*e_a + o_b*e_b)/l_fin; write final ml.
// grid 1024, 256 thr: block covers 16 rows x 64 d.
// ---------------------------------------------------------------------------
__global__ __launch_bounds__(256) void attn_merge(
    const float* __restrict__ po, const float* __restrict__ mlh,
    __bf16* __restrict__ vecb, float* __restrict__ ml)
{
  const int row = blockIdx.x * 16 + (threadIdx.x >> 4);
  const int dq = threadIdx.x & 15;
  const float2 a = *(const float2*)(mlh + (size_t)row * 2);
  const float2 bm = *(const float2*)(mlh + ((size_t)16384 + row) * 2);
  const float mf = fmaxf(a.x, bm.x);
  const float ea = __expf(a.x - mf), eb = __expf(bm.x - mf);
  const float lf = a.y * ea + bm.y * eb;
  f32x4 oa = *(const f32x4*)(po + (size_t)row * 64 + dq * 4);
  f32x4 ob = *(const f32x4*)(po + ((size_t)16384 + row) * 64 + dq * 4);
  const float inv = 1.f / lf;
  bhalf4 ov;
#pragma unroll
  for (int r = 0; r < 4; ++r) ov[r] = (__bf16)((oa[r] * ea + ob[r] * eb) * inv);
  const int plane = row >> 9, i = row & 511, b = plane >> 3, n = plane & 7;
  *(bhalf4*)(vecb + ((size_t)i * 4 + b) * 512 + n * 64 + dq * 4) = ov;
  if (dq == 0) { ml[(size_t)row * 2] = mf; ml[(size_t)row * 2 + 1] = lf; }
}

// ---------------------------------------------------------------------------
// am_final (unchanged from r6)
// ---------------------------------------------------------------------------
__global__ __launch_bounds__(256) void am_final(
    const __bf16* __restrict__ pb, const float* __restrict__ ms,
    const float* __restrict__ ml, float* __restrict__ am)
{
  const int i = blockIdx.x;
  const int tid = threadIdx.x;
  const int t0 = tid << 3;
  const int tile = t0 >> 7;
  const bool valid = tile <= ((1536 + (i | 31)) >> 7);
  f32x4 a0 = {0.f, 0.f, 0.f, 0.f}, a1 = {0.f, 0.f, 0.f, 0.f};
#pragma unroll 4
  for (int p = 0; p < 32; ++p) {
    const float2 mlv = *(const float2*)(ml + ((size_t)p * 512 + i) * 2);
    float wgt = 0.f;
    if (valid)
      wgt = __expf(ms[((size_t)p * 16 + tile) * 512 + i] - mlv.x) / mlv.y;
    bhalf8 v = *(const bhalf8*)(pb + ((size_t)p * 512 + i) * 2048 + t0);
    a0[0] += wgt * (float)v[0];
    a0[1] += wgt * (float)v[1];
    a0[2] += wgt * (float)v[2];
    a0[3] += wgt * (float)v[3];
    a1[0] += wgt * (float)v[4];
    a1[1] += wgt * (float)v[5];
    a1[2] += wgt * (float)v[6];
    a1[3] += wgt * (float)v[7];
  }
  const float sc = 1.f / 32.f;
  *(f32x4*)(am + (size_t)i * 2048 + t0)     = a0 * sc;
  *(f32x4*)(am + (size_t)i * 2048 + t0 + 4) = a1 * sc;
}

// ---------------------------------------------------------------------------
// Residual + LayerNorm
// ---------------------------------------------------------------------------
__global__ __launch_bounds__(256) void ln_f32(
    const float* __restrict__ x, const float* __restrict__ ao,
    const float* __restrict__ g, const float* __restrict__ bb,
    float* __restrict__ out)
{
  const int row = blockIdx.x;
  const int tid = threadIdx.x;
  const size_t base = (size_t)row * 512;
  const float y0 = x[base + tid] + ao[base + tid];
  const float y1 = x[base + 256 + tid] + ao[base + 256 + tid];
  float s  = y0 + y1;
  float ss = y0 * y0 + y1 * y1;
#pragma unroll
  for (int off = 32; off > 0; off >>= 1) {
    s  += __shfl_xor(s, off);
    ss += __shfl_xor(ss, off);
  }
  __shared__ float sred[4], ssred[4], stat[2];
  const int w = tid >> 6;
  if ((tid & 63) == 0) { sred[w] = s; ssred[w] = ss; }
  __syncthreads();
  if (tid == 0) {
    const float S  = sred[0] + sred[1] + sred[2] + sred[3];
    const float SS = ssred[0] + ssred[1] + ssred[2] + ssred[3];
    const float mu = S * (1.f / 512.f);
    const float var = SS * (1.f / 512.f) - mu * mu;
    stat[0] = mu;
    stat[1] = rsqrtf(var + 1e-5f);
  }
  __syncthreads();
  const float mu = stat[0], rs = stat[1];
  out[base + tid]       = (y0 - mu) * rs * g[tid] + bb[tid];
  out[base + 256 + tid] = (y1 - mu) * rs * g[256 + tid] + bb[256 + tid];
}

// ---------------------------------------------------------------------------
// Launch. ws layout (bf16 elem offsets):
//   vtb  @ 0           4,194,304   (V^T; written by vtrans)
//   po   @ 4,194,304   (2,097,152 f32 = 8MB; -> aof f32 overlay after merge)
//   kvb  @ 8,388,608   8,388,608
//   relb @ 16,777,216  4,194,304
//   qup  @ 20,971,520  1,048,576
//   qvp  @ 22,020,096  1,048,576
//   vecb @ 23,068,672  1,048,576
//   Wt   @ 24,117,248  1,310,720   (wq|wkv|wrel|wo transposed, contiguous)
//   ml   @ 25,427,968  (32,768 f32)
//   ms   @ 25,493,504  (262,144 f32)
//   pb   @ 26,017,792  33,554,432
//   mlh  @ 59,572,224  (65,536 f32)  -> total ~119.4 MB
// ---------------------------------------------------------------------------
extern "C" void kernel_launch(void* const* d_in, const int* in_sizes, int n_in,
                              void* d_out, int out_size, void* d_ws, size_t ws_size,
                              hipStream_t stream)
{
  (void)in_sizes; (void)n_in; (void)out_size; (void)ws_size;
  const float* x      = (const float*)d_in[0];
  const float* memory = (const float*)d_in[1];
  const float* pos    = (const float*)d_in[2];
  const float* pbu    = (const float*)d_in[3];
  const float* pbv    = (const float*)d_in[4];
  const float* indice = (const float*)d_in[6];
  const float* W_q    = (const float*)d_in[7];
  const float* W_kv   = (const float*)d_in[8];
  const float* W_rel  = (const float*)d_in[9];
  const float* W_o    = (const float*)d_in[10];
  const float* ln_g   = (const float*)d_in[11];
  const float* ln_b   = (const float*)d_in[12];

  float* out = (float*)d_out;
  float* am  = out + 1048576;

  __bf16* ws    = (__bf16*)d_ws;
  __bf16* vtb   = ws;
  float*  po    = (float*)(ws + 4194304);
  float*  aof   = po;                       // overlay after merge
  __bf16* kvb   = ws + 8388608;
  __bf16* relb  = ws + 16777216;
  __bf16* qup   = ws + 20971520;
  __bf16* qvp   = ws + 22020096;
  __bf16* vecb  = ws + 23068672;
  __bf16* wt    = ws + 24117248;
  __bf16* wqt   = wt;
  __bf16* wkvt  = wt + 512 * 512;
  __bf16* wrelt = wt + 1536 * 512;
  __bf16* wot   = wt + 2048 * 512;
  float*  ml    = (float*)(ws + 25427968);
  float*  ms    = (float*)(ws + 25493504);
  __bf16* pbuf  = ws + 26017792;
  float*  mlh   = (float*)(ws + 59572224);

  transcast_all<<<dim3(8, 640), 256, 0, stream>>>(W_q, W_kv, W_rel, W_o, wt);

  // q = x @ W_q (with Q epilogue)
  gemm_bf16<2, 1><<<dim3(16, 4), 256, 0, stream>>>(x, x, 2048, wqt, (void*)qup,
                                                   2048, 512, 512, pbu, pbv, qup, qvp);
  // kv = concat(memory, x) @ W_kv
  gemm_bf16<0, 1><<<dim3(64, 8), 256, 0, stream>>>(memory, x, 6144, wkvt, kvb,
                                                   8192, 1024, 512,
                                                   nullptr, nullptr, nullptr, nullptr);
  // rel = pos @ W_rel
  gemm_bf16<0, 1><<<dim3(64, 4), 256, 0, stream>>>(pos, pos, 8192, wrelt, relb,
                                                   8192, 512, 512,
                                                   nullptr, nullptr, nullptr, nullptr);

  vtrans<<<dim3(32, 32), 256, 0, stream>>>(kvb, vtb);

  attn_v4<<<1024, 512, 0, stream>>>(qup, qvp, kvb, relb, vtb, indice,
                                    po, mlh, pbuf, ms);
  attn_merge<<<1024, 256, 0, stream>>>(po, mlh, vecb, ml);

  am_final<<<512, 256, 0, stream>>>(pbuf, ms, ml, am);

  // attn_out = vec @ W_o
  gemm_bf16<1, 0><<<dim3(16, 4), 256, 0, stream>>>(vecb, vecb, 2048, wot, aof,
                                                   2048, 512, 512,
                                                   nullptr, nullptr, nullptr, nullptr);
  ln_f32<<<2048, 256, 0, stream>>>(x, aof, ln_g, ln_b, out);
}